// Round 12
// baseline (1280.856 us; speedup 1.0000x reference)
//
#include <hip/hip_runtime.h>
#include <cstdint>
#include <cstddef>

// RNG scheme for reproducing jax.random.uniform(jax.random.key(42), (8,2048,16,512)):
//   0: threefry_partitionable (counter = (0, i)), bits = out0 ^ out1   [verified passing]
#define RNG_SCHEME 0

#define N_TOK 16384      // B*T
#define DIM   1024       // D
#define NGRP  16         // V
#define NCODE 512        // K
#define GDIM  64         // d

typedef float v2f __attribute__((ext_vector_type(2)));

// ---------------- Threefry-2x32, key = (0, 42) ----------------
__device__ __forceinline__ uint2 threefry_0_42(uint32_t x0, uint32_t x1) {
  const uint32_t ks0 = 0u;
  const uint32_t ks1 = 42u;
  const uint32_t ks2 = 0x1BD11BDAu ^ 0u ^ 42u;
  x0 += ks0; x1 += ks1;
#define TF_R(r) { x0 += x1; x1 = (x1 << (r)) | (x1 >> (32 - (r))); x1 ^= x0; }
  TF_R(13) TF_R(15) TF_R(26) TF_R(6)
  x0 += ks1; x1 += ks2 + 1u;
  TF_R(17) TF_R(29) TF_R(16) TF_R(24)
  x0 += ks2; x1 += ks0 + 2u;
  TF_R(13) TF_R(15) TF_R(26) TF_R(6)
  x0 += ks0; x1 += ks1 + 3u;
  TF_R(17) TF_R(29) TF_R(16) TF_R(24)
  x0 += ks1; x1 += ks2 + 4u;
  TF_R(13) TF_R(15) TF_R(26) TF_R(6)
  x0 += ks2; x1 += ks0 + 5u;
#undef TF_R
  return make_uint2(x0, x1);
}

// u in [0,1) exactly as jax: (bits>>9 | 0x3f800000) bitcast - 1.0f
__device__ __forceinline__ float u_from_bits(uint32_t bits) {
  return __uint_as_float((bits >> 9) | 0x3f800000u) - 1.0f;
}

// gumbel = -log(-log(u+1e-8) + 1e-8), ops ordered as the reference.
// fp-monotone nondecreasing in bits (every step is monotone).
__device__ __forceinline__ float gumbel_from_bits(uint32_t bits) {
  float u = u_from_bits(bits);
  float w = (-logf(u + 1e-8f)) + 1e-8f;
  return -logf(w);
}

// monotone float->uint map: preserves total order for non-NaN; equal iff bit-identical
__device__ __forceinline__ uint32_t mono_u32(float z) {
  uint32_t b = __float_as_uint(z);
  return b ^ ((uint32_t)(((int32_t)b) >> 31) | 0x80000000u);
}

// ---------------- zero helper ----------------
__global__ __launch_bounds__(256) void k_zero(float* __restrict__ p, int n) {
  int i = blockIdx.x * 256 + threadIdx.x;
  if (i < n) p[i] = 0.f;
}

// ---------------- c2 table + per-group threshold ----------------
__global__ __launch_bounds__(512) void k_c2(const float* __restrict__ cb,
                                            float* __restrict__ c2tab,
                                            float* __restrict__ thrv) {
  const int v = blockIdx.x, k = threadIdx.x;  // 16 x 512
  const float* cp = cb + (size_t)(v * NCODE + k) * GDIM;
  float s = 0.f;
#pragma unroll 4
  for (int d4 = 0; d4 < 16; ++d4) {
    float4 c = *(const float4*)(cp + d4 * 4);
    s += c.x * c.x + c.y * c.y + c.z * c.z + c.w * c.w;
  }
  c2tab[v * NCODE + k] = s;
  float m = s;
#pragma unroll
  for (int off = 1; off < 64; off <<= 1) m = fmaxf(m, __shfl_xor(m, off, 64));
  __shared__ float pm[8];
  if ((k & 63) == 0) pm[k >> 6] = m;
  __syncthreads();
  if (k == 0) {
    float mm = pm[0];
#pragma unroll
    for (int w = 1; w < 8; ++w) mm = fmaxf(mm, pm[w]);
    thrv[v] = 2.0f * sqrtf(mm) + 0.01f;
  }
}

// ---------------- fp32 NT GEMM (r7 structure + packed-fp32 inner accumulate) ----
// 128x64 tile, 256 thr, 8x4/thr, BK=16, single-buffer. Geometry is the proven
// local optimum (four restructures failed: r2/r6/r8/r10) -- memory patterns,
// LDS layout, staging, and barriers are byte-identical to the 452-us kernel.
// ONLY change: innermost accumulate re-typed to v2f so the backend can emit
// v_pk_fma_f32 (dual fp32 FMA, VOP3P) -- 16 packed vs 32 scalar FMA issues.
// Per-element FMA trees unchanged (pk-fma = two independent IEEE FMAs) ->
// bit-identical C and q2w. If the compiler declines to pack: identical scalar
// codegen, neutral.
__global__ __launch_bounds__(256) void gemm_nt(
    const float* __restrict__ A, const float* __restrict__ B,
    const float* __restrict__ bias, float* __restrict__ C,
    const float* __restrict__ cbk, const int* __restrict__ gidx,
    float* __restrict__ q2w)
{
  __shared__ float as[16 * 132];   // [k][m], stride 132 (pad, keeps 16B align)
  __shared__ float bs[16 * 68];    // [k][n], stride 68
  __shared__ float red[128 * 16];  // q2 reduction scratch

  const int tid = threadIdx.x;
  const int tx = tid & 15;         // n
  const int ty = tid >> 4;         // m
  const int m0 = blockIdx.x * 128;
  const int n0 = blockIdx.y * 64;

  v2f acc[8][2] = {};              // acc[r][0]={n0,n1}, acc[r][1]={n2,n3}

  for (int kt = 0; kt < 64; ++kt) {
    __syncthreads();
#pragma unroll
    for (int i = 0; i < 2; ++i) {
      int f = tid + 256 * i;
      int m_l = f >> 2, k4 = f & 3;
      const float* src;
      if (gidx) {
        int vp = kt >> 2;
        int row = gidx[(m0 + m_l) * NGRP + vp];
        src = cbk + ((size_t)(vp * NCODE + row) * GDIM + (kt & 3) * 16 + k4 * 4);
      } else {
        src = A + ((size_t)(m0 + m_l) * DIM + kt * 16 + k4 * 4);
      }
      float4 a4 = *(const float4*)src;
      as[(k4 * 4 + 0) * 132 + m_l] = a4.x;
      as[(k4 * 4 + 1) * 132 + m_l] = a4.y;
      as[(k4 * 4 + 2) * 132 + m_l] = a4.z;
      as[(k4 * 4 + 3) * 132 + m_l] = a4.w;
    }
    {
      int n_l = tid >> 2, k4 = tid & 3;
      float4 b4 = *(const float4*)(B + ((size_t)(n0 + n_l) * DIM + kt * 16 + k4 * 4));
      bs[(k4 * 4 + 0) * 68 + n_l] = b4.x;
      bs[(k4 * 4 + 1) * 68 + n_l] = b4.y;
      bs[(k4 * 4 + 2) * 68 + n_l] = b4.z;
      bs[(k4 * 4 + 3) * 68 + n_l] = b4.w;
    }
    __syncthreads();
#pragma unroll
    for (int k = 0; k < 16; ++k) {
      float4 a0 = *(const float4*)&as[k * 132 + ty * 8];
      float4 a1 = *(const float4*)&as[k * 132 + ty * 8 + 4];
      float4 b0 = *(const float4*)&bs[k * 68 + tx * 4];
      float av[8] = {a0.x, a0.y, a0.z, a0.w, a1.x, a1.y, a1.z, a1.w};
      v2f b01 = {b0.x, b0.y};
      v2f b23 = {b0.z, b0.w};
#pragma unroll
      for (int r = 0; r < 8; ++r) {
        v2f a2 = {av[r], av[r]};   // splat: op_sel-foldable, no extra mov
        acc[r][0] += a2 * b01;     // lanes: n0 += a*b.x, n1 += a*b.y
        acc[r][1] += a2 * b23;     // lanes: n2 += a*b.z, n3 += a*b.w
      }
    }
  }

  const float4 bb = *(const float4*)(bias + n0 + tx * 4);
#pragma unroll
  for (int r = 0; r < 8; ++r) {
    const int m = m0 + ty * 8 + r;
    float4 c;
    c.x = acc[r][0].x + bb.x; c.y = acc[r][0].y + bb.y;
    c.z = acc[r][1].x + bb.z; c.w = acc[r][1].y + bb.w;
    *(float4*)(C + (size_t)m * DIM + n0 + tx * 4) = c;
    if (q2w) red[(ty * 8 + r) * 16 + tx] = c.x * c.x + c.y * c.y + c.z * c.z + c.w * c.w;
  }
  if (q2w) {
    __syncthreads();
    if (tid < 128) {
      float s = 0.f;
#pragma unroll
      for (int x = 0; x < 16; ++x) s += red[tid * 16 + x];
      q2w[(size_t)(m0 + tid) * NGRP + blockIdx.y] = s;
    }
  }
}

// ---------------- candidate scoring helper (exact z) ----------------
__device__ __forceinline__ unsigned long long cand_key(
    const float* __restrict__ qp, const float* __restrict__ cp,
    float c2k, float q2v, uint32_t bits, int k)
{
  float acc = 0.f;
#pragma unroll 4
  for (int d4 = 0; d4 < 16; ++d4) {
    float4 qv = *(const float4*)(qp + d4 * 4);
    float4 cv = *(const float4*)(cp + d4 * 4);
    acc += qv.x * cv.x + qv.y * cv.y + qv.z * cv.z + qv.w * cv.w;
  }
  float g = gumbel_from_bits(bits);
  float z = (-sqrtf(fmaxf((q2v + c2k) - 2.0f * acc, 0.0f))) + g;
  return ((unsigned long long)mono_u32(z) << 32) | (uint32_t)(1023 - k);
}

// ---------------- K2: wave-per-token + single-candidate fast path (r11-verified) ----
__global__ __launch_bounds__(256) void k2_select(
    const float* __restrict__ q, const float* __restrict__ q2w,
    const float* __restrict__ cb, const float* __restrict__ c2tab,
    const float* __restrict__ thrv, float* __restrict__ counts,
    int* __restrict__ idxw)
{
  const int tid = threadIdx.x;
  const int lane = tid & 63, wv = tid >> 6;
  const int v   = blockIdx.y;                  // 0..15
  const int tok = blockIdx.x * 4 + wv;         // 0..16383

  // phase A: threefry bits for my 8 codes (exact stream: ctr = base + k)
  const uint32_t base = ((uint32_t)(tok * NGRP + v)) << 9;
  uint32_t bits[8];
#pragma unroll
  for (int i = 0; i < 8; ++i) {
    uint2 r = threefry_0_42(0u, base + (uint32_t)(lane + 64 * i));
    bits[i] = r.x ^ r.y;
  }

  // phase B: wave max of bits (== max u == max g, fp-monotone)
  uint32_t m = bits[0];
#pragma unroll
  for (int i = 1; i < 8; ++i) m = bits[i] > m ? bits[i] : m;
#pragma unroll
  for (int off = 1; off < 64; off <<= 1) {
    uint32_t o = __shfl_xor(m, off, 64);
    if (o > m) m = o;
  }

  // phase C: u* threshold (wave-uniform; every lane computes it)
  const float gmax = gumbel_from_bits(m);
  const float inner = gmax - thrv[v];
  const float wstar = expf(-inner) - 1e-8f;    // > 0 since inner <= ~16
  const float ustar = expf(-wstar) - 1e-8f - 1e-6f;

  // phase D0: candidate census via ballots (wave-uniform results)
  int total = 0, win = 0;
#pragma unroll
  for (int i = 0; i < 8; ++i) {
    unsigned long long mk = __ballot(u_from_bits(bits[i]) >= ustar);
    total += __popcll(mk);
    if (mk) win = __builtin_ctzll(mk) + 64 * i;
  }

  int fi;
  if (total == 1) {
    // sole candidate == provable winner: no memory, no dot, no butterfly
    fi = win;
  } else {
    // phase D1: exact evaluation (byte-identical to the verified r7 path)
    const float q2v = q2w[tok * NGRP + v];
    const float* qp = q + (size_t)tok * DIM + v * GDIM;
    unsigned long long K = 0ull;
#pragma unroll 1
    for (int i = 0; i < 8; ++i) {
      if (u_from_bits(bits[i]) >= ustar) {
        const int k = lane + 64 * i;
        unsigned long long t = cand_key(qp, cb + (size_t)(v * NCODE + k) * GDIM,
                                        c2tab[v * NCODE + k], q2v, bits[i], k);
        if (t > K) K = t;
      }
    }
#pragma unroll
    for (int off = 1; off < 64; off <<= 1) {
      unsigned long long O = __shfl_xor(K, off, 64);
      if (O > K) K = O;
    }
    // fi in [0,511] always; '&511' hardens the impossible K==0 path.
    fi = (1023 - (int)(K & 0xFFFFFFFFu)) & 511;
  }

  if (lane == 0) {
    idxw[tok * NGRP + v] = fi;
    atomicAdd(&counts[v * NCODE + fi], 1.0f);
  }
}

// ---------------- targets ----------------
__global__ __launch_bounds__(256) void k_targets(const int* __restrict__ idxw, float* __restrict__ out) {
  int bt = blockIdx.x * 256 + threadIdx.x;  // 0..16383
  const int* p = idxw + bt * NGRP;
  int s = 0;
#pragma unroll
  for (int v = 0; v < NGRP; ++v) s += p[v] * (v * NCODE);
  out[bt] = (float)s;
}

// ---------------- diversity loss (parallel over v; r10-verified) ----------------
__global__ __launch_bounds__(512) void k_losses(const float* __restrict__ counts, float* __restrict__ out) {
  __shared__ float partial[8];
  const int k = threadIdx.x;           // 0..511
  const int v = blockIdx.x;            // 0..15
  const int lane = k & 63, wv = k >> 6;
  const float invN = 1.0f / 16384.0f;  // pow2: identical to division
  const float logK = logf(512.0f);
  float p = counts[v * NCODE + k] * invN;
  float term = p * logf(p + 1e-8f);
  float s = term;
#pragma unroll
  for (int off = 1; off < 64; off <<= 1) s += __shfl_xor(s, off, 64);
  if (lane == 0) partial[wv] = s;
  __syncthreads();
  if (k == 0) {
    float t = 0.f;
#pragma unroll
    for (int w = 0; w < 8; ++w) t += partial[w];
    float ent = -t;
    atomicAdd(out, 0.1f * (-((ent / logK) / 16.0f)));
  }
}

// ---------------- launch ----------------
extern "C" void kernel_launch(void* const* d_in, const int* in_sizes, int n_in,
                              void* d_out, int out_size, void* d_ws, size_t ws_size,
                              hipStream_t stream) {
  const float* features  = (const float*)d_in[0];  // (8,2048,1024)
  const float* codebooks = (const float*)d_in[1];  // (16,512,64)
  const float* Wq   = (const float*)d_in[2];       // (1024,1024)
  const float* bq   = (const float*)d_in[3];       // (1024)
  const float* Wout = (const float*)d_in[4];       // (1024,1024)
  const float* bout = (const float*)d_in[5];       // (1024)

  float* out = (float*)d_out;
  float* quantized = out;                 // 16,777,216
  float* targets   = out + 16777216;      // 16,384
  float* losses    = out + 16793600;      // 1

  float* ws     = (float*)d_ws;
  float* q      = ws;                     // 16,777,216 f
  float* q2w    = ws + 16777216;          // 262,144 f
  float* counts = ws + 17039360;          // 8,192 f
  int*   idxw   = (int*)(ws + 17047552);  // 262,144 i  (total 69.2 MB)

  // c2 table + thresholds live in the quantized output region as scratch;
  // k2 is the only consumer, and gemm2 (last kernel) overwrites the region.
  float* c2tab = quantized;               // 8,192 f
  float* thrv  = quantized + 8192;        // 16 f

  hipLaunchKernelGGL(k_zero, dim3(32), dim3(256), 0, stream, counts, NGRP * NCODE);
  hipLaunchKernelGGL(k_zero, dim3(1), dim3(256), 0, stream, losses, 1);
  hipLaunchKernelGGL(k_c2, dim3(16), dim3(512), 0, stream, codebooks, c2tab, thrv);
  hipLaunchKernelGGL(gemm_nt, dim3(128, 16), dim3(256), 0, stream,
                     features, Wq, bq, q, (const float*)nullptr, (const int*)nullptr, q2w);
  hipLaunchKernelGGL(k2_select, dim3(4096, 16), dim3(256), 0, stream,
                     q, q2w, codebooks, c2tab, thrv, counts, idxw);
  hipLaunchKernelGGL(k_targets, dim3(64), dim3(256), 0, stream, idxw, targets);
  hipLaunchKernelGGL(k_losses, dim3(16), dim3(512), 0, stream, counts, losses);
  hipLaunchKernelGGL(gemm_nt, dim3(128, 16), dim3(256), 0, stream,
                     (const float*)nullptr, Wout, bout, quantized, codebooks, idxw,
                     (float*)nullptr);
}

// Round 14
// 1224.936 us; speedup vs baseline: 1.0457x; 1.0457x over previous
//
#include <hip/hip_runtime.h>
#include <cstdint>
#include <cstddef>

// RNG scheme for reproducing jax.random.uniform(jax.random.key(42), (8,2048,16,512)):
//   0: threefry_partitionable (counter = (0, i)), bits = out0 ^ out1   [verified passing]
#define RNG_SCHEME 0

#define N_TOK 16384      // B*T
#define DIM   1024       // D
#define NGRP  16         // V
#define NCODE 512        // K
#define GDIM  64         // d

// ---------------- Threefry-2x32, key = (0, 42) ----------------
__device__ __forceinline__ uint2 threefry_0_42(uint32_t x0, uint32_t x1) {
  const uint32_t ks0 = 0u;
  const uint32_t ks1 = 42u;
  const uint32_t ks2 = 0x1BD11BDAu ^ 0u ^ 42u;
  x0 += ks0; x1 += ks1;
#define TF_R(r) { x0 += x1; x1 = (x1 << (r)) | (x1 >> (32 - (r))); x1 ^= x0; }
  TF_R(13) TF_R(15) TF_R(26) TF_R(6)
  x0 += ks1; x1 += ks2 + 1u;
  TF_R(17) TF_R(29) TF_R(16) TF_R(24)
  x0 += ks2; x1 += ks0 + 2u;
  TF_R(13) TF_R(15) TF_R(26) TF_R(6)
  x0 += ks0; x1 += ks1 + 3u;
  TF_R(17) TF_R(29) TF_R(16) TF_R(24)
  x0 += ks1; x1 += ks2 + 4u;
  TF_R(13) TF_R(15) TF_R(26) TF_R(6)
  x0 += ks2; x1 += ks0 + 5u;
#undef TF_R
  return make_uint2(x0, x1);
}

// u in [0,1) exactly as jax: (bits>>9 | 0x3f800000) bitcast - 1.0f
__device__ __forceinline__ float u_from_bits(uint32_t bits) {
  return __uint_as_float((bits >> 9) | 0x3f800000u) - 1.0f;
}

// gumbel = -log(-log(u+1e-8) + 1e-8), ops ordered as the reference.
// fp-monotone nondecreasing in bits (every step is monotone).
__device__ __forceinline__ float gumbel_from_bits(uint32_t bits) {
  float u = u_from_bits(bits);
  float w = (-logf(u + 1e-8f)) + 1e-8f;
  return -logf(w);
}

// monotone float->uint map: preserves total order for non-NaN; equal iff bit-identical
__device__ __forceinline__ uint32_t mono_u32(float z) {
  uint32_t b = __float_as_uint(z);
  return b ^ ((uint32_t)(((int32_t)b) >> 31) | 0x80000000u);
}

// global->LDS 16B DMA (no VGPR round-trip). LDS dest is wave-uniform base +
// lane*16 (per-lane &as[f*4] satisfies this exactly); global src is per-lane.
// size=16 is a literal. __syncthreads() drains vmcnt before any ds_read.
// [m97-verified pattern]
__device__ __forceinline__ void gload_lds16(const float* g, float* l) {
  __builtin_amdgcn_global_load_lds(
      (const __attribute__((address_space(1))) unsigned int*)g,
      (__attribute__((address_space(3))) unsigned int*)l, 16, 0, 0);
}

// ---------------- zero helper ----------------
__global__ __launch_bounds__(256) void k_zero(float* __restrict__ p, int n) {
  int i = blockIdx.x * 256 + threadIdx.x;
  if (i < n) p[i] = 0.f;
}

// ---------------- c2 table + per-group threshold ----------------
__global__ __launch_bounds__(512) void k_c2(const float* __restrict__ cb,
                                            float* __restrict__ c2tab,
                                            float* __restrict__ thrv) {
  const int v = blockIdx.x, k = threadIdx.x;  // 16 x 512
  const float* cp = cb + (size_t)(v * NCODE + k) * GDIM;
  float s = 0.f;
#pragma unroll 4
  for (int d4 = 0; d4 < 16; ++d4) {
    float4 c = *(const float4*)(cp + d4 * 4);
    s += c.x * c.x + c.y * c.y + c.z * c.z + c.w * c.w;
  }
  c2tab[v * NCODE + k] = s;
  float m = s;
#pragma unroll
  for (int off = 1; off < 64; off <<= 1) m = fmaxf(m, __shfl_xor(m, off, 64));
  __shared__ float pm[8];
  if ((k & 63) == 0) pm[k >> 6] = m;
  __syncthreads();
  if (k == 0) {
    float mm = pm[0];
#pragma unroll
    for (int w = 1; w < 8; ++w) mm = fmaxf(mm, pm[w]);
    thrv[v] = 2.0f * sqrtf(mm) + 0.01f;
  }
}

// ---------------- fp32 NT GEMM: r7 geometry + global_load_lds A-staging ----------
// 128x64 tile, 256 thr, 8x4/thr, BK=16, single-buffer, scalar FMA (v2f acc
// reverted: r12 showed FETCH x7.5 / +32 us). Changes vs the 446-us r7 kernel:
//  * A-tile staged via global_load_lds 16B DMA into a LINEAR [slot][k] layout
//    (slot = f>>2, dest = &as[f*4] -- linear in lane). Removes 2 VGPR
//    round-trips + 8 ds_write_b32 + addressing per K-step per thread.
//  * Rows parity-swizzled at the SOURCE: slot s holds global row m = s^((s>>3)&1)
//    (involution; XOR of bit0 doesn't alter bit3, so it self-inverts).
//    A-read ds_read_b128 banks: ((r&1)^(ty&1))*16 + k4*4 -> 2-way = free
//    (m136). Linear dest + pre-swizzled source + swizzled read (rule #21).
//  * Inner loop k4-chunked, kk ascending -> per-output k-order still 0..15:
//    bit-identical C and q2w. B staging/reads byte-identical to r7.
__global__ __launch_bounds__(256) void gemm_nt(
    const float* __restrict__ A, const float* __restrict__ B,
    const float* __restrict__ bias, float* __restrict__ C,
    const float* __restrict__ cbk, const int* __restrict__ gidx,
    float* __restrict__ q2w)
{
  __shared__ __align__(16) float as[128 * 16];  // [slot][k] linear, 8192 B
  __shared__ float bs[16 * 68];                 // [k][n], stride 68, 4352 B
  __shared__ float red[128 * 16];               // q2 scratch, 8192 B

  const int tid = threadIdx.x;
  const int tx = tid & 15;         // n
  const int ty = tid >> 4;         // m
  const int m0 = blockIdx.x * 128;
  const int n0 = blockIdx.y * 64;

  float acc[8][4] = {};

  for (int kt = 0; kt < 64; ++kt) {
    __syncthreads();
    // stage B first (reg path): its ds_write waits on its own load; the A DMA
    // issued after it stays in flight underneath (FIFO vmcnt).
    {
      int n_l = tid >> 2, k4 = tid & 3;
      float4 b4 = *(const float4*)(B + ((size_t)(n0 + n_l) * DIM + kt * 16 + k4 * 4));
      bs[(k4 * 4 + 0) * 68 + n_l] = b4.x;
      bs[(k4 * 4 + 1) * 68 + n_l] = b4.y;
      bs[(k4 * 4 + 2) * 68 + n_l] = b4.z;
      bs[(k4 * 4 + 3) * 68 + n_l] = b4.w;
    }
    // stage A: 2 x 16B DMA / thread. f -> slot s = f>>2, k4 = f&3;
    // global row m = s ^ ((s>>3)&1)  (parity involution, see header comment)
#pragma unroll
    for (int i = 0; i < 2; ++i) {
      int f = tid + 256 * i;
      int s = f >> 2, k4 = f & 3;
      int m_l = s ^ ((s >> 3) & 1);
      const float* src;
      if (gidx) {
        int vp = kt >> 2;
        int row = gidx[(m0 + m_l) * NGRP + vp];
        src = cbk + ((size_t)(vp * NCODE + row) * GDIM + (kt & 3) * 16 + k4 * 4);
      } else {
        src = A + ((size_t)(m0 + m_l) * DIM + kt * 16 + k4 * 4);
      }
      gload_lds16(src, &as[f * 4]);
    }
    __syncthreads();
#pragma unroll 1
    for (int k4 = 0; k4 < 4; ++k4) {
      float4 bv0 = *(const float4*)&bs[(k4 * 4 + 0) * 68 + tx * 4];
      float4 bv1 = *(const float4*)&bs[(k4 * 4 + 1) * 68 + tx * 4];
      float4 bv2 = *(const float4*)&bs[(k4 * 4 + 2) * 68 + tx * 4];
      float4 bv3 = *(const float4*)&bs[(k4 * 4 + 3) * 68 + tx * 4];
#pragma unroll
      for (int r = 0; r < 8; ++r) {
        const int pm = (ty * 8 + r) ^ (ty & 1);
        float4 ar = *(const float4*)&as[pm * 16 + k4 * 4];
        // kk ascending => per-output k-order identical to the r7 kernel
        acc[r][0] += ar.x * bv0.x; acc[r][1] += ar.x * bv0.y;
        acc[r][2] += ar.x * bv0.z; acc[r][3] += ar.x * bv0.w;
        acc[r][0] += ar.y * bv1.x; acc[r][1] += ar.y * bv1.y;
        acc[r][2] += ar.y * bv1.z; acc[r][3] += ar.y * bv1.w;
        acc[r][0] += ar.z * bv2.x; acc[r][1] += ar.z * bv2.y;
        acc[r][2] += ar.z * bv2.z; acc[r][3] += ar.z * bv2.w;
        acc[r][0] += ar.w * bv3.x; acc[r][1] += ar.w * bv3.y;
        acc[r][2] += ar.w * bv3.z; acc[r][3] += ar.w * bv3.w;
      }
    }
  }

  const float4 bb = *(const float4*)(bias + n0 + tx * 4);
#pragma unroll
  for (int r = 0; r < 8; ++r) {
    const int m = m0 + ty * 8 + r;
    float4 c;
    c.x = acc[r][0] + bb.x; c.y = acc[r][1] + bb.y;
    c.z = acc[r][2] + bb.z; c.w = acc[r][3] + bb.w;
    *(float4*)(C + (size_t)m * DIM + n0 + tx * 4) = c;
    if (q2w) red[(ty * 8 + r) * 16 + tx] = c.x * c.x + c.y * c.y + c.z * c.z + c.w * c.w;
  }
  if (q2w) {
    __syncthreads();
    if (tid < 128) {
      float s = 0.f;
#pragma unroll
      for (int x = 0; x < 16; ++x) s += red[tid * 16 + x];
      q2w[(size_t)(m0 + tid) * NGRP + blockIdx.y] = s;
    }
  }
}

// ---------------- candidate scoring helper (exact z) ----------------
__device__ __forceinline__ unsigned long long cand_key(
    const float* __restrict__ qp, const float* __restrict__ cp,
    float c2k, float q2v, uint32_t bits, int k)
{
  float acc = 0.f;
#pragma unroll 4
  for (int d4 = 0; d4 < 16; ++d4) {
    float4 qv = *(const float4*)(qp + d4 * 4);
    float4 cv = *(const float4*)(cp + d4 * 4);
    acc += qv.x * cv.x + qv.y * cv.y + qv.z * cv.z + qv.w * cv.w;
  }
  float g = gumbel_from_bits(bits);
  float z = (-sqrtf(fmaxf((q2v + c2k) - 2.0f * acc, 0.0f))) + g;
  return ((unsigned long long)mono_u32(z) << 32) | (uint32_t)(1023 - k);
}

// ---------------- K2: wave-per-token + single-candidate fast path (r11-verified) ----
__global__ __launch_bounds__(256) void k2_select(
    const float* __restrict__ q, const float* __restrict__ q2w,
    const float* __restrict__ cb, const float* __restrict__ c2tab,
    const float* __restrict__ thrv, float* __restrict__ counts,
    int* __restrict__ idxw)
{
  const int tid = threadIdx.x;
  const int lane = tid & 63, wv = tid >> 6;
  const int v   = blockIdx.y;                  // 0..15
  const int tok = blockIdx.x * 4 + wv;         // 0..16383

  // phase A: threefry bits for my 8 codes (exact stream: ctr = base + k)
  const uint32_t base = ((uint32_t)(tok * NGRP + v)) << 9;
  uint32_t bits[8];
#pragma unroll
  for (int i = 0; i < 8; ++i) {
    uint2 r = threefry_0_42(0u, base + (uint32_t)(lane + 64 * i));
    bits[i] = r.x ^ r.y;
  }

  // phase B: wave max of bits (== max u == max g, fp-monotone)
  uint32_t m = bits[0];
#pragma unroll
  for (int i = 1; i < 8; ++i) m = bits[i] > m ? bits[i] : m;
#pragma unroll
  for (int off = 1; off < 64; off <<= 1) {
    uint32_t o = __shfl_xor(m, off, 64);
    if (o > m) m = o;
  }

  // phase C: u* threshold (wave-uniform; every lane computes it)
  const float gmax = gumbel_from_bits(m);
  const float inner = gmax - thrv[v];
  const float wstar = expf(-inner) - 1e-8f;    // > 0 since inner <= ~16
  const float ustar = expf(-wstar) - 1e-8f - 1e-6f;

  // phase D0: candidate census via ballots (wave-uniform results)
  int total = 0, win = 0;
#pragma unroll
  for (int i = 0; i < 8; ++i) {
    unsigned long long mk = __ballot(u_from_bits(bits[i]) >= ustar);
    total += __popcll(mk);
    if (mk) win = __builtin_ctzll(mk) + 64 * i;
  }

  int fi;
  if (total == 1) {
    // sole candidate == provable winner: no memory, no dot, no butterfly
    fi = win;
  } else {
    // phase D1: exact evaluation (byte-identical to the verified r7 path)
    const float q2v = q2w[tok * NGRP + v];
    const float* qp = q + (size_t)tok * DIM + v * GDIM;
    unsigned long long K = 0ull;
#pragma unroll 1
    for (int i = 0; i < 8; ++i) {
      if (u_from_bits(bits[i]) >= ustar) {
        const int k = lane + 64 * i;
        unsigned long long t = cand_key(qp, cb + (size_t)(v * NCODE + k) * GDIM,
                                        c2tab[v * NCODE + k], q2v, bits[i], k);
        if (t > K) K = t;
      }
    }
#pragma unroll
    for (int off = 1; off < 64; off <<= 1) {
      unsigned long long O = __shfl_xor(K, off, 64);
      if (O > K) K = O;
    }
    // fi in [0,511] always; '&511' hardens the impossible K==0 path.
    fi = (1023 - (int)(K & 0xFFFFFFFFu)) & 511;
  }

  if (lane == 0) {
    idxw[tok * NGRP + v] = fi;
    atomicAdd(&counts[v * NCODE + fi], 1.0f);
  }
}

// ---------------- targets ----------------
__global__ __launch_bounds__(256) void k_targets(const int* __restrict__ idxw, float* __restrict__ out) {
  int bt = blockIdx.x * 256 + threadIdx.x;  // 0..16383
  const int* p = idxw + bt * NGRP;
  int s = 0;
#pragma unroll
  for (int v = 0; v < NGRP; ++v) s += p[v] * (v * NCODE);
  out[bt] = (float)s;
}

// ---------------- diversity loss (parallel over v; r10-verified) ----------------
__global__ __launch_bounds__(512) void k_losses(const float* __restrict__ counts, float* __restrict__ out) {
  __shared__ float partial[8];
  const int k = threadIdx.x;           // 0..511
  const int v = blockIdx.x;            // 0..15
  const int lane = k & 63, wv = k >> 6;
  const float invN = 1.0f / 16384.0f;  // pow2: identical to division
  const float logK = logf(512.0f);
  float p = counts[v * NCODE + k] * invN;
  float term = p * logf(p + 1e-8f);
  float s = term;
#pragma unroll
  for (int off = 1; off < 64; off <<= 1) s += __shfl_xor(s, off, 64);
  if (lane == 0) partial[wv] = s;
  __syncthreads();
  if (k == 0) {
    float t = 0.f;
#pragma unroll
    for (int w = 0; w < 8; ++w) t += partial[w];
    float ent = -t;
    atomicAdd(out, 0.1f * (-((ent / logK) / 16.0f)));
  }
}

// ---------------- launch ----------------
extern "C" void kernel_launch(void* const* d_in, const int* in_sizes, int n_in,
                              void* d_out, int out_size, void* d_ws, size_t ws_size,
                              hipStream_t stream) {
  const float* features  = (const float*)d_in[0];  // (8,2048,1024)
  const float* codebooks = (const float*)d_in[1];  // (16,512,64)
  const float* Wq   = (const float*)d_in[2];       // (1024,1024)
  const float* bq   = (const float*)d_in[3];       // (1024)
  const float* Wout = (const float*)d_in[4];       // (1024,1024)
  const float* bout = (const float*)d_in[5];       // (1024)

  float* out = (float*)d_out;
  float* quantized = out;                 // 16,777,216
  float* targets   = out + 16777216;      // 16,384
  float* losses    = out + 16793600;      // 1

  float* ws     = (float*)d_ws;
  float* q      = ws;                     // 16,777,216 f
  float* q2w    = ws + 16777216;          // 262,144 f
  float* counts = ws + 17039360;          // 8,192 f
  int*   idxw   = (int*)(ws + 17047552);  // 262,144 i  (total 69.2 MB)

  // c2 table + thresholds live in the quantized output region as scratch;
  // k2 is the only consumer, and gemm2 (last kernel) overwrites the region.
  float* c2tab = quantized;               // 8,192 f
  float* thrv  = quantized + 8192;        // 16 f

  hipLaunchKernelGGL(k_zero, dim3(32), dim3(256), 0, stream, counts, NGRP * NCODE);
  hipLaunchKernelGGL(k_zero, dim3(1), dim3(256), 0, stream, losses, 1);
  hipLaunchKernelGGL(k_c2, dim3(16), dim3(512), 0, stream, codebooks, c2tab, thrv);
  hipLaunchKernelGGL(gemm_nt, dim3(128, 16), dim3(256), 0, stream,
                     features, Wq, bq, q, (const float*)nullptr, (const int*)nullptr, q2w);
  hipLaunchKernelGGL(k2_select, dim3(4096, 16), dim3(256), 0, stream,
                     q, q2w, codebooks, c2tab, thrv, counts, idxw);
  hipLaunchKernelGGL(k_targets, dim3(64), dim3(256), 0, stream, idxw, targets);
  hipLaunchKernelGGL(k_losses, dim3(16), dim3(512), 0, stream, counts, losses);
  hipLaunchKernelGGL(gemm_nt, dim3(128, 16), dim3(256), 0, stream,
                     (const float*)nullptr, Wout, bout, quantized, codebooks, idxw,
                     (float*)nullptr);
}

// Round 15
// 947.461 us; speedup vs baseline: 1.3519x; 1.2929x over previous
//
#include <hip/hip_runtime.h>
#include <cstdint>
#include <cstddef>

// RNG scheme for reproducing jax.random.uniform(jax.random.key(42), (8,2048,16,512)):
//   0: threefry_partitionable (counter = (0, i)), bits = out0 ^ out1   [verified passing]
#define RNG_SCHEME 0

#define N_TOK 16384      // B*T
#define DIM   1024       // D
#define NGRP  16         // V
#define NCODE 512        // K
#define GDIM  64         // d

// ---------------- Threefry-2x32, key = (0, 42) ----------------
__device__ __forceinline__ uint2 threefry_0_42(uint32_t x0, uint32_t x1) {
  const uint32_t ks0 = 0u;
  const uint32_t ks1 = 42u;
  const uint32_t ks2 = 0x1BD11BDAu ^ 0u ^ 42u;
  x0 += ks0; x1 += ks1;
#define TF_R(r) { x0 += x1; x1 = (x1 << (r)) | (x1 >> (32 - (r))); x1 ^= x0; }
  TF_R(13) TF_R(15) TF_R(26) TF_R(6)
  x0 += ks1; x1 += ks2 + 1u;
  TF_R(17) TF_R(29) TF_R(16) TF_R(24)
  x0 += ks2; x1 += ks0 + 2u;
  TF_R(13) TF_R(15) TF_R(26) TF_R(6)
  x0 += ks0; x1 += ks1 + 3u;
  TF_R(17) TF_R(29) TF_R(16) TF_R(24)
  x0 += ks1; x1 += ks2 + 4u;
  TF_R(13) TF_R(15) TF_R(26) TF_R(6)
  x0 += ks2; x1 += ks0 + 5u;
#undef TF_R
  return make_uint2(x0, x1);
}

// u in [0,1) exactly as jax: (bits>>9 | 0x3f800000) bitcast - 1.0f
__device__ __forceinline__ float u_from_bits(uint32_t bits) {
  return __uint_as_float((bits >> 9) | 0x3f800000u) - 1.0f;
}

// gumbel = -log(-log(u+1e-8) + 1e-8), ops ordered as the reference.
// fp-monotone nondecreasing in bits (every step is monotone).
__device__ __forceinline__ float gumbel_from_bits(uint32_t bits) {
  float u = u_from_bits(bits);
  float w = (-logf(u + 1e-8f)) + 1e-8f;
  return -logf(w);
}

// monotone float->uint map: preserves total order for non-NaN; equal iff bit-identical
__device__ __forceinline__ uint32_t mono_u32(float z) {
  uint32_t b = __float_as_uint(z);
  return b ^ ((uint32_t)(((int32_t)b) >> 31) | 0x80000000u);
}

// ---------------- zero helper ----------------
__global__ __launch_bounds__(256) void k_zero(float* __restrict__ p, int n) {
  int i = blockIdx.x * 256 + threadIdx.x;
  if (i < n) p[i] = 0.f;
}

// ---------------- c2 table + per-group threshold ----------------
__global__ __launch_bounds__(512) void k_c2(const float* __restrict__ cb,
                                            float* __restrict__ c2tab,
                                            float* __restrict__ thrv) {
  const int v = blockIdx.x, k = threadIdx.x;  // 16 x 512
  const float* cp = cb + (size_t)(v * NCODE + k) * GDIM;
  float s = 0.f;
#pragma unroll 4
  for (int d4 = 0; d4 < 16; ++d4) {
    float4 c = *(const float4*)(cp + d4 * 4);
    s += c.x * c.x + c.y * c.y + c.z * c.z + c.w * c.w;
  }
  c2tab[v * NCODE + k] = s;
  float m = s;
#pragma unroll
  for (int off = 1; off < 64; off <<= 1) m = fmaxf(m, __shfl_xor(m, off, 64));
  __shared__ float pm[8];
  if ((k & 63) == 0) pm[k >> 6] = m;
  __syncthreads();
  if (k == 0) {
    float mm = pm[0];
#pragma unroll
    for (int w = 1; w < 8; ++w) mm = fmaxf(mm, pm[w]);
    thrv[v] = 2.0f * sqrtf(mm) + 0.01f;
  }
}

// ---------------- fp32 NT GEMM (r7 verbatim: 128x64 tile, 256 thr, 8x4/thr) ----
// Single-buffer, two barriers per K-step. Measured 446 us / 44 VGPR / occ 44%.
// Six variants failed or were neutral (reg-dbuf, BK=32, 128x128, 512-thr,
// v2f pack, DMA A-staging): this structure is occupancy/latency-balanced.
// KEEP AS IS. (gidx path retained but unused now - gemm2 is replaced.)
__global__ __launch_bounds__(256) void gemm_nt(
    const float* __restrict__ A, const float* __restrict__ B,
    const float* __restrict__ bias, float* __restrict__ C,
    const float* __restrict__ cbk, const int* __restrict__ gidx,
    float* __restrict__ q2w)
{
  __shared__ float as[16 * 132];   // [k][m], stride 132 (pad, keeps 16B align)
  __shared__ float bs[16 * 68];    // [k][n], stride 68
  __shared__ float red[128 * 16];  // q2 reduction scratch

  const int tid = threadIdx.x;
  const int tx = tid & 15;         // n
  const int ty = tid >> 4;         // m
  const int m0 = blockIdx.x * 128;
  const int n0 = blockIdx.y * 64;

  float acc[8][4] = {};

  for (int kt = 0; kt < 64; ++kt) {
    __syncthreads();
#pragma unroll
    for (int i = 0; i < 2; ++i) {
      int f = tid + 256 * i;
      int m_l = f >> 2, k4 = f & 3;
      const float* src;
      if (gidx) {
        int vp = kt >> 2;
        int row = gidx[(m0 + m_l) * NGRP + vp];
        src = cbk + ((size_t)(vp * NCODE + row) * GDIM + (kt & 3) * 16 + k4 * 4);
      } else {
        src = A + ((size_t)(m0 + m_l) * DIM + kt * 16 + k4 * 4);
      }
      float4 a4 = *(const float4*)src;
      as[(k4 * 4 + 0) * 132 + m_l] = a4.x;
      as[(k4 * 4 + 1) * 132 + m_l] = a4.y;
      as[(k4 * 4 + 2) * 132 + m_l] = a4.z;
      as[(k4 * 4 + 3) * 132 + m_l] = a4.w;
    }
    {
      int n_l = tid >> 2, k4 = tid & 3;
      float4 b4 = *(const float4*)(B + ((size_t)(n0 + n_l) * DIM + kt * 16 + k4 * 4));
      bs[(k4 * 4 + 0) * 68 + n_l] = b4.x;
      bs[(k4 * 4 + 1) * 68 + n_l] = b4.y;
      bs[(k4 * 4 + 2) * 68 + n_l] = b4.z;
      bs[(k4 * 4 + 3) * 68 + n_l] = b4.w;
    }
    __syncthreads();
#pragma unroll
    for (int k = 0; k < 16; ++k) {
      float4 a0 = *(const float4*)&as[k * 132 + ty * 8];
      float4 a1 = *(const float4*)&as[k * 132 + ty * 8 + 4];
      float4 b0 = *(const float4*)&bs[k * 68 + tx * 4];
      float av[8] = {a0.x, a0.y, a0.z, a0.w, a1.x, a1.y, a1.z, a1.w};
      float bv[4] = {b0.x, b0.y, b0.z, b0.w};
#pragma unroll
      for (int r = 0; r < 8; ++r)
#pragma unroll
        for (int j = 0; j < 4; ++j) acc[r][j] += av[r] * bv[j];
    }
  }

  const float4 bb = *(const float4*)(bias + n0 + tx * 4);
#pragma unroll
  for (int r = 0; r < 8; ++r) {
    const int m = m0 + ty * 8 + r;
    float4 c;
    c.x = acc[r][0] + bb.x; c.y = acc[r][1] + bb.y;
    c.z = acc[r][2] + bb.z; c.w = acc[r][3] + bb.w;
    *(float4*)(C + (size_t)m * DIM + n0 + tx * 4) = c;
    if (q2w) red[(ty * 8 + r) * 16 + tx] = c.x * c.x + c.y * c.y + c.z * c.z + c.w * c.w;
  }
  if (q2w) {
    __syncthreads();
    if (tid < 128) {
      float s = 0.f;
#pragma unroll
      for (int x = 0; x < 16; ++x) s += red[tid * 16 + x];
      q2w[(size_t)(m0 + tid) * NGRP + blockIdx.y] = s;
    }
  }
}

// ---------------- P table: P[v][k][n] = sum_d cb[v][k][d] * Wout[n][v*64+d] ----
// Replaces GEMM2's inner product: quantized[m] = bout + sum_v P[v][idx[m,v]].
// 8192x1024 output, K=64 (1.07 GFLOP). Same tile/staging/FMA pattern as
// gemm_nt (d ascending per output) -- just 4 K-steps. No bias here.
// grid (64, 16): blockIdx.x = v*4 + row-block (128 rows each); blockIdx.y = n-tile.
__global__ __launch_bounds__(256) void k_pvk(
    const float* __restrict__ cb, const float* __restrict__ Wout,
    float* __restrict__ P)
{
  __shared__ float as[16 * 132];
  __shared__ float bs[16 * 68];

  const int tid = threadIdx.x;
  const int tx = tid & 15;
  const int ty = tid >> 4;
  const int v  = blockIdx.x >> 2;
  const int k0 = (blockIdx.x & 3) * 128;
  const int n0 = blockIdx.y * 64;

  float acc[8][4] = {};

  for (int kt = 0; kt < 4; ++kt) {
    __syncthreads();
#pragma unroll
    for (int i = 0; i < 2; ++i) {
      int f = tid + 256 * i;
      int m_l = f >> 2, k4 = f & 3;
      float4 a4 = *(const float4*)(cb + ((size_t)(v * NCODE + k0 + m_l) * GDIM + kt * 16 + k4 * 4));
      as[(k4 * 4 + 0) * 132 + m_l] = a4.x;
      as[(k4 * 4 + 1) * 132 + m_l] = a4.y;
      as[(k4 * 4 + 2) * 132 + m_l] = a4.z;
      as[(k4 * 4 + 3) * 132 + m_l] = a4.w;
    }
    {
      int n_l = tid >> 2, k4 = tid & 3;
      float4 b4 = *(const float4*)(Wout + (size_t)(n0 + n_l) * DIM + v * GDIM + kt * 16 + k4 * 4);
      bs[(k4 * 4 + 0) * 68 + n_l] = b4.x;
      bs[(k4 * 4 + 1) * 68 + n_l] = b4.y;
      bs[(k4 * 4 + 2) * 68 + n_l] = b4.z;
      bs[(k4 * 4 + 3) * 68 + n_l] = b4.w;
    }
    __syncthreads();
#pragma unroll
    for (int k = 0; k < 16; ++k) {
      float4 a0 = *(const float4*)&as[k * 132 + ty * 8];
      float4 a1 = *(const float4*)&as[k * 132 + ty * 8 + 4];
      float4 b0 = *(const float4*)&bs[k * 68 + tx * 4];
      float av[8] = {a0.x, a0.y, a0.z, a0.w, a1.x, a1.y, a1.z, a1.w};
      float bv[4] = {b0.x, b0.y, b0.z, b0.w};
#pragma unroll
      for (int r = 0; r < 8; ++r)
#pragma unroll
        for (int j = 0; j < 4; ++j) acc[r][j] += av[r] * bv[j];
    }
  }

#pragma unroll
  for (int r = 0; r < 8; ++r) {
    float4 c = {acc[r][0], acc[r][1], acc[r][2], acc[r][3]};
    *(float4*)(P + (size_t)(v * NCODE + k0 + ty * 8 + r) * DIM + n0 + tx * 4) = c;
  }
}

// ---------------- gather-sum: quantized[m] = bout + sum_v P[v][idx[m,v]] ----
// grid (16384), 256 thr; thread owns 4 output dims. 16 coalesced 1KB/wave row
// reads per v (P is 33.5 MB, L3-resident). Sum v ascending, bout added last.
__global__ __launch_bounds__(256) void k_gather(
    const float* __restrict__ P, const int* __restrict__ idxw,
    const float* __restrict__ bout, float* __restrict__ outq)
{
  const int m = blockIdx.x;
  const int tid = threadIdx.x;
  __shared__ int sidx[16];
  if (tid < 16) sidx[tid] = idxw[m * NGRP + tid];
  __syncthreads();

  float4 a = {0.f, 0.f, 0.f, 0.f};
#pragma unroll
  for (int v = 0; v < 16; ++v) {
    const float4 p = *(const float4*)(P + (size_t)(v * NCODE + sidx[v]) * DIM + tid * 4);
    a.x += p.x; a.y += p.y; a.z += p.z; a.w += p.w;
  }
  const float4 b = *(const float4*)(bout + tid * 4);
  a.x += b.x; a.y += b.y; a.z += b.z; a.w += b.w;
  *(float4*)(outq + (size_t)m * DIM + tid * 4) = a;
}

// ---------------- candidate scoring helper (exact z) ----------------
__device__ __forceinline__ unsigned long long cand_key(
    const float* __restrict__ qp, const float* __restrict__ cp,
    float c2k, float q2v, uint32_t bits, int k)
{
  float acc = 0.f;
#pragma unroll 4
  for (int d4 = 0; d4 < 16; ++d4) {
    float4 qv = *(const float4*)(qp + d4 * 4);
    float4 cv = *(const float4*)(cp + d4 * 4);
    acc += qv.x * cv.x + qv.y * cv.y + qv.z * cv.z + qv.w * cv.w;
  }
  float g = gumbel_from_bits(bits);
  float z = (-sqrtf(fmaxf((q2v + c2k) - 2.0f * acc, 0.0f))) + g;
  return ((unsigned long long)mono_u32(z) << 32) | (uint32_t)(1023 - k);
}

// ---------------- K2: wave-per-token + single-candidate fast path (r11-verified) ----
__global__ __launch_bounds__(256) void k2_select(
    const float* __restrict__ q, const float* __restrict__ q2w,
    const float* __restrict__ cb, const float* __restrict__ c2tab,
    const float* __restrict__ thrv, float* __restrict__ counts,
    int* __restrict__ idxw)
{
  const int tid = threadIdx.x;
  const int lane = tid & 63, wv = tid >> 6;
  const int v   = blockIdx.y;                  // 0..15
  const int tok = blockIdx.x * 4 + wv;         // 0..16383

  // phase A: threefry bits for my 8 codes (exact stream: ctr = base + k)
  const uint32_t base = ((uint32_t)(tok * NGRP + v)) << 9;
  uint32_t bits[8];
#pragma unroll
  for (int i = 0; i < 8; ++i) {
    uint2 r = threefry_0_42(0u, base + (uint32_t)(lane + 64 * i));
    bits[i] = r.x ^ r.y;
  }

  // phase B: wave max of bits (== max u == max g, fp-monotone)
  uint32_t m = bits[0];
#pragma unroll
  for (int i = 1; i < 8; ++i) m = bits[i] > m ? bits[i] : m;
#pragma unroll
  for (int off = 1; off < 64; off <<= 1) {
    uint32_t o = __shfl_xor(m, off, 64);
    if (o > m) m = o;
  }

  // phase C: u* threshold (wave-uniform; every lane computes it)
  const float gmax = gumbel_from_bits(m);
  const float inner = gmax - thrv[v];
  const float wstar = expf(-inner) - 1e-8f;    // > 0 since inner <= ~16
  const float ustar = expf(-wstar) - 1e-8f - 1e-6f;

  // phase D0: candidate census via ballots (wave-uniform results)
  int total = 0, win = 0;
#pragma unroll
  for (int i = 0; i < 8; ++i) {
    unsigned long long mk = __ballot(u_from_bits(bits[i]) >= ustar);
    total += __popcll(mk);
    if (mk) win = __builtin_ctzll(mk) + 64 * i;
  }

  int fi;
  if (total == 1) {
    // sole candidate == provable winner: no memory, no dot, no butterfly
    fi = win;
  } else {
    // phase D1: exact evaluation (byte-identical to the verified r7 path)
    const float q2v = q2w[tok * NGRP + v];
    const float* qp = q + (size_t)tok * DIM + v * GDIM;
    unsigned long long K = 0ull;
#pragma unroll 1
    for (int i = 0; i < 8; ++i) {
      if (u_from_bits(bits[i]) >= ustar) {
        const int k = lane + 64 * i;
        unsigned long long t = cand_key(qp, cb + (size_t)(v * NCODE + k) * GDIM,
                                        c2tab[v * NCODE + k], q2v, bits[i], k);
        if (t > K) K = t;
      }
    }
#pragma unroll
    for (int off = 1; off < 64; off <<= 1) {
      unsigned long long O = __shfl_xor(K, off, 64);
      if (O > K) K = O;
    }
    // fi in [0,511] always; '&511' hardens the impossible K==0 path.
    fi = (1023 - (int)(K & 0xFFFFFFFFu)) & 511;
  }

  if (lane == 0) {
    idxw[tok * NGRP + v] = fi;
    atomicAdd(&counts[v * NCODE + fi], 1.0f);
  }
}

// ---------------- targets ----------------
__global__ __launch_bounds__(256) void k_targets(const int* __restrict__ idxw, float* __restrict__ out) {
  int bt = blockIdx.x * 256 + threadIdx.x;  // 0..16383
  const int* p = idxw + bt * NGRP;
  int s = 0;
#pragma unroll
  for (int v = 0; v < NGRP; ++v) s += p[v] * (v * NCODE);
  out[bt] = (float)s;
}

// ---------------- diversity loss (parallel over v; r10-verified) ----------------
__global__ __launch_bounds__(512) void k_losses(const float* __restrict__ counts, float* __restrict__ out) {
  __shared__ float partial[8];
  const int k = threadIdx.x;           // 0..511
  const int v = blockIdx.x;            // 0..15
  const int lane = k & 63, wv = k >> 6;
  const float invN = 1.0f / 16384.0f;  // pow2: identical to division
  const float logK = logf(512.0f);
  float p = counts[v * NCODE + k] * invN;
  float term = p * logf(p + 1e-8f);
  float s = term;
#pragma unroll
  for (int off = 1; off < 64; off <<= 1) s += __shfl_xor(s, off, 64);
  if (lane == 0) partial[wv] = s;
  __syncthreads();
  if (k == 0) {
    float t = 0.f;
#pragma unroll
    for (int w = 0; w < 8; ++w) t += partial[w];
    float ent = -t;
    atomicAdd(out, 0.1f * (-((ent / logK) / 16.0f)));
  }
}

// ---------------- launch ----------------
extern "C" void kernel_launch(void* const* d_in, const int* in_sizes, int n_in,
                              void* d_out, int out_size, void* d_ws, size_t ws_size,
                              hipStream_t stream) {
  const float* features  = (const float*)d_in[0];  // (8,2048,1024)
  const float* codebooks = (const float*)d_in[1];  // (16,512,64)
  const float* Wq   = (const float*)d_in[2];       // (1024,1024)
  const float* bq   = (const float*)d_in[3];       // (1024)
  const float* Wout = (const float*)d_in[4];       // (1024,1024)
  const float* bout = (const float*)d_in[5];       // (1024)

  float* out = (float*)d_out;
  float* quantized = out;                 // 16,777,216
  float* targets   = out + 16777216;      // 16,384
  float* losses    = out + 16793600;      // 1

  float* ws     = (float*)d_ws;
  float* q      = ws;                     // 16,777,216 f (q, later reused for P)
  float* q2w    = ws + 16777216;          // 262,144 f
  float* counts = ws + 17039360;          // 8,192 f
  int*   idxw   = (int*)(ws + 17047552);  // 262,144 i  (total 69.2 MB)

  // c2 table + thresholds live in the quantized output region as scratch;
  // k2 is the only consumer; k_gather (last kernel) overwrites the region.
  float* c2tab = quantized;               // 8,192 f
  float* thrv  = quantized + 8192;        // 16 f

  // P table (8192 x 1024 f = 33.5 MB) overwrites q AFTER k2 has consumed it
  // (stream order). q region is 64 MB, plenty.
  float* P = q;

  hipLaunchKernelGGL(k_zero, dim3(32), dim3(256), 0, stream, counts, NGRP * NCODE);
  hipLaunchKernelGGL(k_zero, dim3(1), dim3(256), 0, stream, losses, 1);
  hipLaunchKernelGGL(k_c2, dim3(16), dim3(512), 0, stream, codebooks, c2tab, thrv);
  hipLaunchKernelGGL(gemm_nt, dim3(128, 16), dim3(256), 0, stream,
                     features, Wq, bq, q, (const float*)nullptr, (const int*)nullptr, q2w);
  hipLaunchKernelGGL(k2_select, dim3(4096, 16), dim3(256), 0, stream,
                     q, q2w, codebooks, c2tab, thrv, counts, idxw);
  hipLaunchKernelGGL(k_targets, dim3(64), dim3(256), 0, stream, idxw, targets);
  hipLaunchKernelGGL(k_losses, dim3(16), dim3(512), 0, stream, counts, losses);
  hipLaunchKernelGGL(k_pvk, dim3(64, 16), dim3(256), 0, stream, codebooks, Wout, P);
  hipLaunchKernelGGL(k_gather, dim3(16384), dim3(256), 0, stream, P, idxw, bout, quantized);
}